// Round 12
// baseline (4942.830 us; speedup 1.0000x reference)
//
#include <hip/hip_runtime.h>

#define TT 512
#define II 64
#define HH 256
#define NG 16          // batch groups (16 rows each)
#define NS 8           // gate slices per group (32 channels each)
#define FST 520        // flag lines per group (>= TT+1), 32 u16 (64B) each

typedef _Float16 half8 __attribute__((ext_vector_type(8)));
typedef float f32x4 __attribute__((ext_vector_type(4)));
typedef unsigned long long u64;

__device__ __forceinline__ float sigm(float x){ return 1.0f/(1.0f+__expf(-x)); }
__device__ __forceinline__ float tanhf_(float x){ float e=__expf(2.0f*x); return 1.0f-2.0f/(e+1.0f); }

union HU { _Float16 h; unsigned short u; };
__device__ __forceinline__ unsigned short h2u(float f){ HU x; x.h=(_Float16)f; return x.u; }

__device__ __forceinline__ half8 cvt8v(const float* __restrict__ p){
    f32x4 a = *(const f32x4*)p, b = *(const f32x4*)(p+4);
    half8 r;
    r[0]=(_Float16)a[0]; r[1]=(_Float16)a[1]; r[2]=(_Float16)a[2]; r[3]=(_Float16)a[3];
    r[4]=(_Float16)b[0]; r[5]=(_Float16)b[1]; r[6]=(_Float16)b[2]; r[7]=(_Float16)b[3];
    return r;
}

__device__ __forceinline__ void pina(half8& v){ asm volatile("" : "+a"(v)); }
__device__ __forceinline__ void pinv(f32x4& v){ asm volatile("" : "+v"(v)); }

#define MFMA(A,B,C) __builtin_amdgcn_mfma_f32_16x16x32_f16((A),(B),(C),0,0,0)
#define ALOAD64(p)    __hip_atomic_load((p), __ATOMIC_RELAXED, __HIP_MEMORY_SCOPE_AGENT)
#define ASTORE64(p,v) __hip_atomic_store((p), (v), __ATOMIC_RELAXED, __HIP_MEMORY_SCOPE_AGENT)
#define ASTORE16(p,v) __hip_atomic_store((p), (v), __ATOMIC_RELAXED, __HIP_MEMORY_SCOPE_AGENT)
#define ASTORE32(p,v) __hip_atomic_store((p), (v), __ATOMIC_RELAXED, __HIP_MEMORY_SCOPE_AGENT)

// One-shot L1 invalidate (verified correct in r10): subsequent same-wave
// VMEM loads are pipe-ordered after it and re-read the shared XCD L2.
__device__ __forceinline__ void l1inv(){
    asm volatile("buffer_inv sc0" ::: "memory");
}

// Load this lane's 8 MFMA-B fragments (one layer) from a blocked h tile.
__device__ __forceinline__ void load8_mall(const u64* __restrict__ T,
                                           const int fo, half8 (&bh)[8]){
#pragma unroll
    for (int kt=0;kt<8;++kt){
        const u64* p = T + fo + kt*128;
        u64 a = ALOAD64(p), b = ALOAD64(p+1);
        union { u64 u[2]; half8 h; } cv; cv.u[0]=a; cv.u[1]=b;
        bh[kt] = cv.h;
    }
}
__device__ __forceinline__ void load8_l2(const u64* __restrict__ T,
                                         const int fo, half8 (&bh)[8]){
#pragma unroll
    for (int kt=0;kt<8;++kt){
        const u64* p = T + fo + kt*128;
        u64 a = *(volatile const u64*)p, b = *(volatile const u64*)(p+1);
        union { u64 u[2]; half8 h; } cv; cv.u[0]=a; cv.u[1]=b;
        bh[kt] = cv.h;
    }
}

// Persistent gate-sliced, layer-pipelined 2-layer LSTM — HYBRID protocol.
// 128 WGs x 256 thr: group=blockIdx%16, slice=blockIdx/16; wave owns 8 chans.
// Superstep t computes h0(t), h1(t-1).
// DATA: same-XCD verified (HW_REG_XCC_ID) -> write-through stores to shared L2,
//   one buffer_inv per step, plain loads (r10-verified). Else MALL atomics (r7).
// FLAGS: always MALL relaxed atomics (r7-verified; no inv in the spin loop).
__global__ __launch_bounds__(256,1) __attribute__((amdgpu_waves_per_eu(1)))
void lstm_pers(
    const float* __restrict__ x,
    const float* __restrict__ Wih0, const float* __restrict__ Whh0,
    const float* __restrict__ bih0, const float* __restrict__ bhh0,
    const float* __restrict__ Wih1, const float* __restrict__ Whh1,
    const float* __restrict__ bih1, const float* __restrict__ bhh1,
    const float* __restrict__ W1, const float* __restrict__ b1,
    const float* __restrict__ W2, const float* __restrict__ b2,
    unsigned short* __restrict__ flags, unsigned* __restrict__ xccbuf,
    _Float16* __restrict__ hb0, _Float16* __restrict__ hb1,
    float* __restrict__ out)
{
    __shared__ __align__(16) unsigned short twv[4][2][16][8];   // 2 KB
    __shared__ __align__(16) float epi[16*256 + 16*128];        // 24 KB (epilogue)
    __shared__ int s_fast;

    const int tid = threadIdx.x;
    const int w   = tid >> 6;
    const int l   = tid & 63;
    const int lr  = l & 15;
    const int lk  = l >> 4;
    const int g   = blockIdx.x & (NG-1);
    const int s   = blockIdx.x >> 4;
    const int gbase = g * 16;
    const int cw  = s*32 + w*8;
    const int wid = s*4 + w;          // wave id in group == chanblock (0..31)

    u64* hb0u = (u64*)hb0;
    u64* hb1u = (u64*)hb1;

    // ---- negotiation A: publish this WG's XCC id (MALL) ----
    if (tid == 0){
        unsigned xcc;
        asm volatile("s_getreg_b32 %0, hwreg(HW_REG_XCC_ID)" : "=s"(xcc));
        ASTORE32(xccbuf + g*8 + s, (xcc & 0xFu) + 1u);
    }

    // ---- resident weight fragments (MFMA A-operand), pinned into AGPRs ----
    half8 wA0[10][2];   // layer0: kt<8 -> Whh0 (K=256), kt=8,9 -> Wih0 (K=64)
    half8 wA1[16][2];   // layer1: kt<8 -> Whh1, kt>=8 -> Wih1
    f32x4 bias0v[2], bias1v[2];
#pragma unroll
    for (int m=0;m<2;++m){
        const int n = (lr&3)*HH + cw + m*4 + (lr>>2);
#pragma unroll
        for (int kt=0;kt<10;++kt){
            const float* src = (kt<8) ? (Whh0 + (size_t)n*HH + kt*32 + lk*8)
                                      : (Wih0 + (size_t)n*II + (kt-8)*32 + lk*8);
            wA0[kt][m] = cvt8v(src);
            pina(wA0[kt][m]);
        }
#pragma unroll
        for (int kt=0;kt<16;++kt){
            const float* src = (kt<8) ? (Whh1 + (size_t)n*HH + kt*32 + lk*8)
                                      : (Wih1 + (size_t)n*HH + (kt-8)*32 + lk*8);
            wA1[kt][m] = cvt8v(src);
            pina(wA1[kt][m]);
        }
        const int cD = cw + m*4 + lk;
#pragma unroll
        for (int j=0;j<4;++j){
            bias0v[m][j] = bih0[j*HH+cD] + bhh0[j*HH+cD];
            bias1v[m][j] = bih1[j*HH+cD] + bhh1[j*HH+cD];
        }
        pinv(bias0v[m]); pinv(bias1v[m]);
    }

    // ---- negotiation B: wait for all 8 slices, verdict = all same XCC ----
    if (tid == 0){
        const u64* xs = (const u64*)(xccbuf + g*8);
        u64 a0,a1,a2,a3;
        for (;;){
            a0 = ALOAD64(xs);   a1 = ALOAD64(xs+1);
            a2 = ALOAD64(xs+2); a3 = ALOAD64(xs+3);
            if ((unsigned)a0 && (a0>>32) && (unsigned)a1 && (a1>>32) &&
                (unsigned)a2 && (a2>>32) && (unsigned)a3 && (a3>>32)) break;
        }
        const u64 rep = (u64)(unsigned)a0 * 0x0000000100000001ull;
        s_fast = (a0==rep && a1==rep && a2==rep && a3==rep) ? 1 : 0;
    }
    __syncthreads();
    const bool fast = (s_fast != 0);

    float c0s0=0.f, c0s1=0.f, c1s0=0.f, c1s1=0.f;
    unsigned short* fgrp = flags + (size_t)g*FST*32;
    const int fo = lk*32 + lr*2;      // per-lane frag base (u64), + kt*128

    // ---- x(0) register prefetch ----
    f32x4 xa, xb, xc, xd;
    {
        const float* xp = x + ((size_t)(gbase+lr)*TT)*II + lk*8;
        xa = *(const f32x4*)xp;      xb = *(const f32x4*)(xp+4);
        xc = *(const f32x4*)(xp+32); xd = *(const f32x4*)(xp+36);
    }

    half8 bh0[8] = {}, bh1[8] = {};   // current-step h fragments (B-operand)

    for (int t=0; t<=TT; ++t){
        f32x4 a0m0 = bias0v[0], a0m1 = bias0v[1];
        f32x4 a1m0 = bias1v[0], a1m1 = bias1v[1];

        // x-part of layer0 from prefetched registers
        if (t < TT){
            half8 bx0, bx1;
#pragma unroll
            for (int j=0;j<4;++j){
                bx0[j]   = (_Float16)xa[j];  bx0[4+j] = (_Float16)xb[j];
                bx1[j]   = (_Float16)xc[j];  bx1[4+j] = (_Float16)xd[j];
            }
            a0m0 = MFMA(wA0[8][0], bx0, a0m0);
            a0m1 = MFMA(wA0[8][1], bx0, a0m1);
            a0m0 = MFMA(wA0[9][0], bx1, a0m0);
            a0m1 = MFMA(wA0[9][1], bx1, a0m1);
        }

        if (t > 0){
            if (t < TT){
#pragma unroll
                for (int kt=0;kt<8;++kt){         // Whh0 * h0(t-1)
                    a0m0 = MFMA(wA0[kt][0], bh0[kt], a0m0);
                    a0m1 = MFMA(wA0[kt][1], bh0[kt], a0m1);
                }
            }
#pragma unroll
            for (int kt=0;kt<8;++kt){             // Wih1 * h0(t-1)
                a1m0 = MFMA(wA1[8+kt][0], bh0[kt], a1m0);
                a1m1 = MFMA(wA1[8+kt][1], bh0[kt], a1m1);
            }
            if (t >= 2){
#pragma unroll
                for (int kt=0;kt<8;++kt){         // Whh1 * h1(t-2)
                    a1m0 = MFMA(wA1[kt][0], bh1[kt], a1m0);
                    a1m1 = MFMA(wA1[kt][1], bh1[kt], a1m1);
                }
            }
        }

        // ---- activations -> wave-local LDS transpose tile ----
        if (t < TT){
            float ig=sigm(a0m0[0]), fg=sigm(a0m0[1]), gg=tanhf_(a0m0[2]), og=sigm(a0m0[3]);
            c0s0 = fg*c0s0 + ig*gg;
            twv[w][0][lr][lk]   = h2u(og*tanhf_(c0s0));
            float ig1=sigm(a0m1[0]), fg1=sigm(a0m1[1]), gg1=tanhf_(a0m1[2]), og1=sigm(a0m1[3]);
            c0s1 = fg1*c0s1 + ig1*gg1;
            twv[w][0][lr][lk+4] = h2u(og1*tanhf_(c0s1));
        }
        if (t > 0){
            float ig=sigm(a1m0[0]), fg=sigm(a1m0[1]), gg=tanhf_(a1m0[2]), og=sigm(a1m0[3]);
            c1s0 = fg*c1s0 + ig*gg;
            twv[w][1][lr][lk]   = h2u(og*tanhf_(c1s0));
            float ig1=sigm(a1m1[0]), fg1=sigm(a1m1[1]), gg1=tanhf_(a1m1[2]), og1=sigm(a1m1[3]);
            c1s1 = fg1*c1s1 + ig1*gg1;
            twv[w][1][lr][lk+4] = h2u(og1*tanhf_(c1s1));
        }
        asm volatile("s_waitcnt lgkmcnt(0)" ::: "memory");

        // x prefetch for t+1 (overlaps the stores below)
        if (t + 1 < TT){
            const float* xp = x + ((size_t)(gbase+lr)*TT + (t+1))*II + lk*8;
            xa = *(const f32x4*)xp;      xb = *(const f32x4*)(xp+4);
            xc = *(const f32x4*)(xp+32); xd = *(const f32x4*)(xp+36);
        }

        // ---- coalesced blocked piece stores: lanes 0..31, one u64 each ----
        if (l < 32){
            const int row = l >> 1, hf = l & 1;
            if (t < TT){
                u64 v = *(const u64*)&twv[w][0][row][hf*4];
                u64* D0 = hb0u + ((size_t)((t&1)*NG + g))*1024 + wid*32 + l;
                if (fast) *(volatile u64*)D0 = v; else ASTORE64(D0, v);
            }
            if (t > 0){
                u64 v = *(const u64*)&twv[w][1][row][hf*4];
                u64* D1 = hb1u + ((size_t)(((t-1)&1)*NG + g))*1024 + wid*32 + l;
                if (fast) *(volatile u64*)D1 = v; else ASTORE64(D1, v);
            }
        }
        asm volatile("s_waitcnt vmcnt(0)" ::: "memory");   // data committed (L2/MALL)
        if (l == 0)
            ASTORE16(&fgrp[(size_t)t*32 + wid], (unsigned short)(t+1));  // MALL flag

        if (t < TT){
            // ---- poll the group flag line via MALL (no L1 involvement) ----
            const u64 pat = 0x0001000100010001ULL * (u64)(t+1);
            const u64* fp = (const u64*)(fgrp + (size_t)t*32);
            for (;;){
                u64 v = (l < 8) ? ALOAD64(fp + l) : pat;
                if (__all(v == pat)) break;
            }
            // ---- one L1 invalidate, then data loads (L2 on fast path) ----
            const u64* T0 = hb0u + ((size_t)((t&1)*NG + g))*1024;
            if (fast){
                l1inv();
                load8_l2(T0, fo, bh0);
            } else {
                load8_mall(T0, fo, bh0);
            }
            if (t >= 1){
                const u64* T1 = hb1u + ((size_t)(((t+1)&1)*NG + g))*1024;
                if (fast) load8_l2(T1, fo, bh1); else load8_mall(T1, fo, bh1);
            }
        }
    }

    // ---- epilogue: slice 0 of each group computes the MLP head ----
    if (s == 0){
        {   // ensure all h1(TT-1) pieces are visible
            const u64 pat = 0x0001000100010001ULL * (u64)(TT+1);
            const u64* fp = (const u64*)(fgrp + (size_t)TT*32);
            for (;;){
                u64 v = (l < 8) ? ALOAD64(fp + l) : pat;
                if (__all(v == pat)) break;
            }
            if (fast) l1inv();
        }
        __syncthreads();
        float* hl  = epi;              // [16][256]
        float* zsh = epi + 16*256;     // [16][128]
        const u64* HL = hb1u + ((size_t)(((TT-1)&1)*NG + g))*1024;
        for (int i = tid; i < 1024; i += 256){
            const int r = i >> 6, q = i & 63;
            const size_t gi = (size_t)(q>>1)*32 + r*2 + (q&1);
            u64 v = fast ? *(volatile const u64*)(HL + gi) : ALOAD64(HL + gi);
            union { u64 u; _Float16 h[4]; } cv; cv.u = v;
#pragma unroll
            for (int e=0;e<4;++e) hl[r*256 + q*4 + e] = (float)cv.h[e];
        }
        __syncthreads();
        for (int idx = tid; idx < 2048; idx += 256){
            const int r = idx >> 7, j = idx & 127;
            const float* wrow = W1 + j*HH;
            const float* hr = hl + r*256;
            float ssum = b1[j];
            for (int k=0;k<HH;k+=4){
                f32x4 wv = *(const f32x4*)(wrow + k);
                ssum += hr[k]*wv[0] + hr[k+1]*wv[1] + hr[k+2]*wv[2] + hr[k+3]*wv[3];
            }
            zsh[r*128 + j] = tanhf_(ssum);
        }
        __syncthreads();
        for (int idx = tid; idx < 1536; idx += 256){
            const int r = idx / 96, o = idx - r*96;
            const float* wrow = W2 + o*128;
            const float* zr = zsh + r*128;
            float ssum = b2[o];
            for (int k=0;k<128;k+=4){
                f32x4 wv = *(const f32x4*)(wrow + k);
                ssum += zr[k]*wv[0] + zr[k+1]*wv[1] + zr[k+2]*wv[2] + zr[k+3]*wv[3];
            }
            out[(size_t)(gbase+r)*96 + o] = ssum;
        }
    }
}

extern "C" void kernel_launch(void* const* d_in, const int* in_sizes, int n_in,
                              void* d_out, int out_size, void* d_ws, size_t ws_size,
                              hipStream_t stream) {
    const float* x    = (const float*)d_in[0];
    const float* Wih0 = (const float*)d_in[1];
    const float* Whh0 = (const float*)d_in[2];
    const float* bih0 = (const float*)d_in[3];
    const float* bhh0 = (const float*)d_in[4];
    const float* Wih1 = (const float*)d_in[5];
    const float* Whh1 = (const float*)d_in[6];
    const float* bih1 = (const float*)d_in[7];
    const float* bhh1 = (const float*)d_in[8];
    const float* W1   = (const float*)d_in[9];
    const float* b1   = (const float*)d_in[10];
    const float* W2   = (const float*)d_in[11];
    const float* b2   = (const float*)d_in[12];

    // workspace: flags 16*520*64 = 532,480 B | xccbuf 512 B | pad
    //            hb0/hb1 blocked: 2 bufs * 16 g * 32 blk * 256 B = 262,144 B each
    unsigned short* flags  = (unsigned short*)d_ws;
    unsigned*       xccbuf = (unsigned*)((char*)d_ws + 532480);
    _Float16* hb0 = (_Float16*)((char*)d_ws + 540672);
    _Float16* hb1 = (_Float16*)((char*)d_ws + 540672 + 262144);

    hipMemsetAsync(d_ws, 0, 540672, stream);   // zero flags + xccbuf (graph-safe)

    hipLaunchKernelGGL(lstm_pers, dim3(NG*NS), dim3(256), 0, stream,
                       x, Wih0, Whh0, bih0, bhh0,
                       Wih1, Whh1, bih1, bhh1,
                       W1, b1, W2, b2,
                       flags, xccbuf, hb0, hb1, (float*)d_out);
}

// Round 15
// 1762.764 us; speedup vs baseline: 2.8040x; 2.8040x over previous
//
#include <hip/hip_runtime.h>

#define TT 512
#define II 64
#define HH 256
#define NG 16          // batch groups (16 rows each)
#define NS 8           // gate slices per group (32 channels each)
#define FST 520        // flag lines per group (>= TT+1), 8 u16 (16B) each

typedef _Float16 half8 __attribute__((ext_vector_type(8)));
typedef float f32x4 __attribute__((ext_vector_type(4)));
typedef unsigned long long u64;

__device__ __forceinline__ float sigm(float x){ return 1.0f/(1.0f+__expf(-x)); }
__device__ __forceinline__ float tanhf_(float x){ float e=__expf(2.0f*x); return 1.0f-2.0f/(e+1.0f); }

union HU { _Float16 h; unsigned short u; };
__device__ __forceinline__ unsigned short h2u(float f){ HU x; x.h=(_Float16)f; return x.u; }

__device__ __forceinline__ half8 cvt8v(const float* __restrict__ p){
    f32x4 a = *(const f32x4*)p, b = *(const f32x4*)(p+4);
    half8 r;
    r[0]=(_Float16)a[0]; r[1]=(_Float16)a[1]; r[2]=(_Float16)a[2]; r[3]=(_Float16)a[3];
    r[4]=(_Float16)b[0]; r[5]=(_Float16)b[1]; r[6]=(_Float16)b[2]; r[7]=(_Float16)b[3];
    return r;
}

// Pin weight fragments into the AGPR file (opaque asm result cannot be
// rematerialized; AGPRs otherwise idle; MFMA reads A from AGPR directly).
__device__ __forceinline__ void pina(half8& v){ asm volatile("" : "+a"(v)); }
__device__ __forceinline__ void pinv(f32x4& v){ asm volatile("" : "+v"(v)); }

#define MFMA(A,B,C) __builtin_amdgcn_mfma_f32_16x16x32_f16((A),(B),(C),0,0,0)
#define ALOAD64(p)    __hip_atomic_load((p), __ATOMIC_RELAXED, __HIP_MEMORY_SCOPE_AGENT)
#define ASTORE64(p,v) __hip_atomic_store((p), (v), __ATOMIC_RELAXED, __HIP_MEMORY_SCOPE_AGENT)
#define ASTORE16(p,v) __hip_atomic_store((p), (v), __ATOMIC_RELAXED, __HIP_MEMORY_SCOPE_AGENT)

// Persistent gate-sliced, layer-pipelined 2-layer LSTM — r7 MALL protocol
// with (a) WG-level flags (8 u16 / 16B line; single-u64-pair poll) and
// (b) cooperative fragment staging through LDS (4x less MALL read traffic).
// 128 WGs x 256 thr: group=blockIdx%16, slice=blockIdx/16; wave owns 8 chans.
// Superstep t computes h0(t) [t<TT] and h1(t-1) [t>0]. All cross-WG data via
// relaxed agent-scope atomics (the only mechanism proven fast+correct here).
__global__ __launch_bounds__(256,1) __attribute__((amdgpu_waves_per_eu(1)))
void lstm_pers(
    const float* __restrict__ x,
    const float* __restrict__ Wih0, const float* __restrict__ Whh0,
    const float* __restrict__ bih0, const float* __restrict__ bhh0,
    const float* __restrict__ Wih1, const float* __restrict__ Whh1,
    const float* __restrict__ bih1, const float* __restrict__ bhh1,
    const float* __restrict__ W1, const float* __restrict__ b1,
    const float* __restrict__ W2, const float* __restrict__ b2,
    unsigned short* __restrict__ flags,
    _Float16* __restrict__ hb0, _Float16* __restrict__ hb1,
    float* __restrict__ out)
{
    // fragment-staging tile: [layer0 kt0..7 | layer1 kt0..7][128 u64] = 16 KB
    __shared__ __align__(16) u64 fsh[16*128];
    // per-wave store-transpose tiles
    __shared__ __align__(16) unsigned short twv[4][2][16][8];   // 2 KB
    __shared__ __align__(16) float epi[16*256 + 16*128];        // 24 KB (epilogue)

    const int tid = threadIdx.x;
    const int w   = tid >> 6;
    const int l   = tid & 63;
    const int lr  = l & 15;
    const int lk  = l >> 4;
    const int g   = blockIdx.x & (NG-1);
    const int s   = blockIdx.x >> 4;
    const int gbase = g * 16;
    const int cw  = s*32 + w*8;
    const int wid = s*4 + w;          // wave id in group == chanblock (0..31)

    u64* hb0u = (u64*)hb0;
    u64* hb1u = (u64*)hb1;

    // ---- resident weight fragments (MFMA A-operand), pinned into AGPRs ----
    half8 wA0[10][2];   // layer0: kt<8 -> Whh0 (K=256), kt=8,9 -> Wih0 (K=64)
    half8 wA1[16][2];   // layer1: kt<8 -> Whh1, kt>=8 -> Wih1
    f32x4 bias0v[2], bias1v[2];
#pragma unroll
    for (int m=0;m<2;++m){
        const int n = (lr&3)*HH + cw + m*4 + (lr>>2);
#pragma unroll
        for (int kt=0;kt<10;++kt){
            const float* src = (kt<8) ? (Whh0 + (size_t)n*HH + kt*32 + lk*8)
                                      : (Wih0 + (size_t)n*II + (kt-8)*32 + lk*8);
            wA0[kt][m] = cvt8v(src);
            pina(wA0[kt][m]);
        }
#pragma unroll
        for (int kt=0;kt<16;++kt){
            const float* src = (kt<8) ? (Whh1 + (size_t)n*HH + kt*32 + lk*8)
                                      : (Wih1 + (size_t)n*HH + (kt-8)*32 + lk*8);
            wA1[kt][m] = cvt8v(src);
            pina(wA1[kt][m]);
        }
        const int cD = cw + m*4 + lk;
#pragma unroll
        for (int j=0;j<4;++j){
            bias0v[m][j] = bih0[j*HH+cD] + bhh0[j*HH+cD];
            bias1v[m][j] = bih1[j*HH+cD] + bhh1[j*HH+cD];
        }
        pinv(bias0v[m]); pinv(bias1v[m]);
    }

    float c0s0=0.f, c0s1=0.f, c1s0=0.f, c1s1=0.f;
    unsigned short* fgrp = flags + (size_t)g*FST*8;
    const int fo = lk*32 + lr*2;      // per-lane frag offset (u64), + kt*128

    // ---- x(0) register prefetch ----
    f32x4 xa, xb, xc, xd;
    {
        const float* xp = x + ((size_t)(gbase+lr)*TT)*II + lk*8;
        xa = *(const f32x4*)xp;      xb = *(const f32x4*)(xp+4);
        xc = *(const f32x4*)(xp+32); xd = *(const f32x4*)(xp+36);
    }

    half8 bh0[8] = {}, bh1[8] = {};   // current-step h fragments (B-operand)

    for (int t=0; t<=TT; ++t){
        f32x4 a0m0 = bias0v[0], a0m1 = bias0v[1];
        f32x4 a1m0 = bias1v[0], a1m1 = bias1v[1];

        // x-part of layer0 from prefetched registers
        if (t < TT){
            half8 bx0, bx1;
#pragma unroll
            for (int j=0;j<4;++j){
                bx0[j]   = (_Float16)xa[j];  bx0[4+j] = (_Float16)xb[j];
                bx1[j]   = (_Float16)xc[j];  bx1[4+j] = (_Float16)xd[j];
            }
            a0m0 = MFMA(wA0[8][0], bx0, a0m0);
            a0m1 = MFMA(wA0[8][1], bx0, a0m1);
            a0m0 = MFMA(wA0[9][0], bx1, a0m0);
            a0m1 = MFMA(wA0[9][1], bx1, a0m1);
        }

        if (t > 0){
            if (t < TT){
#pragma unroll
                for (int kt=0;kt<8;++kt){         // Whh0 * h0(t-1)
                    a0m0 = MFMA(wA0[kt][0], bh0[kt], a0m0);
                    a0m1 = MFMA(wA0[kt][1], bh0[kt], a0m1);
                }
            }
#pragma unroll
            for (int kt=0;kt<8;++kt){             // Wih1 * h0(t-1)
                a1m0 = MFMA(wA1[8+kt][0], bh0[kt], a1m0);
                a1m1 = MFMA(wA1[8+kt][1], bh0[kt], a1m1);
            }
            if (t >= 2){
#pragma unroll
                for (int kt=0;kt<8;++kt){         // Whh1 * h1(t-2)
                    a1m0 = MFMA(wA1[kt][0], bh1[kt], a1m0);
                    a1m1 = MFMA(wA1[kt][1], bh1[kt], a1m1);
                }
            }
        }

        // ---- activations -> wave-local LDS transpose tile ----
        if (t < TT){
            float ig=sigm(a0m0[0]), fg=sigm(a0m0[1]), gg=tanhf_(a0m0[2]), og=sigm(a0m0[3]);
            c0s0 = fg*c0s0 + ig*gg;
            twv[w][0][lr][lk]   = h2u(og*tanhf_(c0s0));
            float ig1=sigm(a0m1[0]), fg1=sigm(a0m1[1]), gg1=tanhf_(a0m1[2]), og1=sigm(a0m1[3]);
            c0s1 = fg1*c0s1 + ig1*gg1;
            twv[w][0][lr][lk+4] = h2u(og1*tanhf_(c0s1));
        }
        if (t > 0){
            float ig=sigm(a1m0[0]), fg=sigm(a1m0[1]), gg=tanhf_(a1m0[2]), og=sigm(a1m0[3]);
            c1s0 = fg*c1s0 + ig*gg;
            twv[w][1][lr][lk]   = h2u(og*tanhf_(c1s0));
            float ig1=sigm(a1m1[0]), fg1=sigm(a1m1[1]), gg1=tanhf_(a1m1[2]), og1=sigm(a1m1[3]);
            c1s1 = fg1*c1s1 + ig1*gg1;
            twv[w][1][lr][lk+4] = h2u(og1*tanhf_(c1s1));
        }
        asm volatile("s_waitcnt lgkmcnt(0)" ::: "memory");

        // x prefetch for t+1 (overlaps the stores below)
        if (t + 1 < TT){
            const float* xp = x + ((size_t)(gbase+lr)*TT + (t+1))*II + lk*8;
            xa = *(const f32x4*)xp;      xb = *(const f32x4*)(xp+4);
            xc = *(const f32x4*)(xp+32); xd = *(const f32x4*)(xp+36);
        }

        // ---- coalesced blocked piece stores: lanes 0..31, one u64 each ----
        if (l < 32){
            const int row = l >> 1, hf = l & 1;
            if (t < TT){
                u64 v = *(const u64*)&twv[w][0][row][hf*4];
                ASTORE64(hb0u + ((size_t)((t&1)*NG + g))*1024 + wid*32 + l, v);
            }
            if (t > 0){
                u64 v = *(const u64*)&twv[w][1][row][hf*4];
                ASTORE64(hb1u + ((size_t)(((t-1)&1)*NG + g))*1024 + wid*32 + l, v);
            }
        }
        asm volatile("s_waitcnt vmcnt(0)" ::: "memory");   // this wave's stores visible
        __syncthreads();                                    // all 4 waves drained
        if (tid == 0)
            ASTORE16(&fgrp[(size_t)t*8 + s], (unsigned short)(t+1));  // WG flag

        if (t < TT){
            // ---- poll the group line: 8 WG slots (2 u64) == t+1 ----
            const u64 pat = 0x0001000100010001ULL * (u64)(t+1);
            const u64* fp = (const u64*)(fgrp + (size_t)t*8);
            for (;;){
                u64 v = (l < 2) ? ALOAD64(fp + l) : pat;
                if (__all(v == pat)) break;
            }
            // ---- cooperative staging: wave w loads kt=2w,2w+1 -> LDS ----
            const int kt0 = 2*w;
            {
                const u64* T0 = hb0u + ((size_t)((t&1)*NG + g))*1024;
                u64 a0 = ALOAD64(T0 + kt0*128 + fo);
                u64 a1 = ALOAD64(T0 + kt0*128 + fo + 1);
                u64 b0 = ALOAD64(T0 + (kt0+1)*128 + fo);
                u64 b1 = ALOAD64(T0 + (kt0+1)*128 + fo + 1);
                fsh[kt0*128 + fo]       = a0;
                fsh[kt0*128 + fo + 1]   = a1;
                fsh[(kt0+1)*128 + fo]   = b0;
                fsh[(kt0+1)*128 + fo+1] = b1;
            }
            if (t >= 1){
                const u64* T1 = hb1u + ((size_t)(((t+1)&1)*NG + g))*1024;
                u64 a0 = ALOAD64(T1 + kt0*128 + fo);
                u64 a1 = ALOAD64(T1 + kt0*128 + fo + 1);
                u64 b0 = ALOAD64(T1 + (kt0+1)*128 + fo);
                u64 b1 = ALOAD64(T1 + (kt0+1)*128 + fo + 1);
                fsh[(8+kt0)*128 + fo]       = a0;
                fsh[(8+kt0)*128 + fo + 1]   = a1;
                fsh[(8+kt0+1)*128 + fo]     = b0;
                fsh[(8+kt0+1)*128 + fo + 1] = b1;
            }
            __syncthreads();   // staging visible (implies lgkm drain)
            // ---- read fragments from LDS into B-registers ----
#pragma unroll
            for (int kt=0;kt<8;++kt){
                union { u64 u[2]; half8 h; } cv;
                cv.u[0] = fsh[kt*128 + fo];
                cv.u[1] = fsh[kt*128 + fo + 1];
                bh0[kt] = cv.h;
            }
            if (t >= 1){
#pragma unroll
                for (int kt=0;kt<8;++kt){
                    union { u64 u[2]; half8 h; } cv;
                    cv.u[0] = fsh[(8+kt)*128 + fo];
                    cv.u[1] = fsh[(8+kt)*128 + fo + 1];
                    bh1[kt] = cv.h;
                }
            }
        }
    }

    // ---- epilogue: slice 0 of each group computes the MLP head ----
    if (s == 0){
        {   // ensure all h1(TT-1) pieces are visible
            const u64 pat = 0x0001000100010001ULL * (u64)(TT+1);
            const u64* fp = (const u64*)(fgrp + (size_t)TT*8);
            for (;;){
                u64 v = (l < 2) ? ALOAD64(fp + l) : pat;
                if (__all(v == pat)) break;
            }
        }
        __syncthreads();
        float* hl  = epi;              // [16][256]
        float* zsh = epi + 16*256;     // [16][128]
        const u64* HL = hb1u + ((size_t)(((TT-1)&1)*NG + g))*1024;
        for (int i = tid; i < 1024; i += 256){
            const int r = i >> 6, q = i & 63;
            const size_t gi = (size_t)(q>>1)*32 + r*2 + (q&1);
            u64 v = ALOAD64(HL + gi);
            union { u64 u; _Float16 h[4]; } cv; cv.u = v;
#pragma unroll
            for (int e=0;e<4;++e) hl[r*256 + q*4 + e] = (float)cv.h[e];
        }
        __syncthreads();
        for (int idx = tid; idx < 2048; idx += 256){
            const int r = idx >> 7, j = idx & 127;
            const float* wrow = W1 + j*HH;
            const float* hr = hl + r*256;
            float ssum = b1[j];
            for (int k=0;k<HH;k+=4){
                f32x4 wv = *(const f32x4*)(wrow + k);
                ssum += hr[k]*wv[0] + hr[k+1]*wv[1] + hr[k+2]*wv[2] + hr[k+3]*wv[3];
            }
            zsh[r*128 + j] = tanhf_(ssum);
        }
        __syncthreads();
        for (int idx = tid; idx < 1536; idx += 256){
            const int r = idx / 96, o = idx - r*96;
            const float* wrow = W2 + o*128;
            const float* zr = zsh + r*128;
            float ssum = b2[o];
            for (int k=0;k<128;k+=4){
                f32x4 wv = *(const f32x4*)(wrow + k);
                ssum += zr[k]*wv[0] + zr[k+1]*wv[1] + zr[k+2]*wv[2] + zr[k+3]*wv[3];
            }
            out[(size_t)(gbase+r)*96 + o] = ssum;
        }
    }
}

extern "C" void kernel_launch(void* const* d_in, const int* in_sizes, int n_in,
                              void* d_out, int out_size, void* d_ws, size_t ws_size,
                              hipStream_t stream) {
    const float* x    = (const float*)d_in[0];
    const float* Wih0 = (const float*)d_in[1];
    const float* Whh0 = (const float*)d_in[2];
    const float* bih0 = (const float*)d_in[3];
    const float* bhh0 = (const float*)d_in[4];
    const float* Wih1 = (const float*)d_in[5];
    const float* Whh1 = (const float*)d_in[6];
    const float* bih1 = (const float*)d_in[7];
    const float* bhh1 = (const float*)d_in[8];
    const float* W1   = (const float*)d_in[9];
    const float* b1   = (const float*)d_in[10];
    const float* W2   = (const float*)d_in[11];
    const float* b2   = (const float*)d_in[12];

    // workspace: flags 16*520*16 B = 133,120 (zeroed; padded to 139,264)
    //            hb0/hb1 blocked: 2 bufs * 16 g * 32 blk * 256 B = 262,144 B each
    unsigned short* flags = (unsigned short*)d_ws;
    _Float16* hb0 = (_Float16*)((char*)d_ws + 139264);
    _Float16* hb1 = (_Float16*)((char*)d_ws + 139264 + 262144);

    hipMemsetAsync(d_ws, 0, 139264, stream);

    hipLaunchKernelGGL(lstm_pers, dim3(NG*NS), dim3(256), 0, stream,
                       x, Wih0, Whh0, bih0, bhh0,
                       Wih1, Whh1, bih1, bhh1,
                       W1, b1, W2, b2,
                       flags, hb0, hb1, (float*)d_out);
}

// Round 17
// 1744.344 us; speedup vs baseline: 2.8336x; 1.0106x over previous
//
#include <hip/hip_runtime.h>

#define TT 512
#define II 64
#define HH 256
#define NG 16          // batch groups (16 rows each)
#define NS 8           // gate slices per group (32 channels each)
#define FST 520        // flag lines per group (>= TT+1), 8 u16 (16B) each

typedef _Float16 half8 __attribute__((ext_vector_type(8)));
typedef float f32x4 __attribute__((ext_vector_type(4)));
typedef unsigned long long u64;

__device__ __forceinline__ float sigm(float x){ return 1.0f/(1.0f+__expf(-x)); }
__device__ __forceinline__ float tanhf_(float x){ float e=__expf(2.0f*x); return 1.0f-2.0f/(e+1.0f); }

union HU { _Float16 h; unsigned short u; };
__device__ __forceinline__ unsigned short h2u(float f){ HU x; x.h=(_Float16)f; return x.u; }

__device__ __forceinline__ half8 cvt8v(const float* __restrict__ p){
    f32x4 a = *(const f32x4*)p, b = *(const f32x4*)(p+4);
    half8 r;
    r[0]=(_Float16)a[0]; r[1]=(_Float16)a[1]; r[2]=(_Float16)a[2]; r[3]=(_Float16)a[3];
    r[4]=(_Float16)b[0]; r[5]=(_Float16)b[1]; r[6]=(_Float16)b[2]; r[7]=(_Float16)b[3];
    return r;
}

// Pin weight fragments into the AGPR file (opaque asm result cannot be
// rematerialized; AGPRs otherwise idle; MFMA reads A from AGPR directly).
__device__ __forceinline__ void pina(half8& v){ asm volatile("" : "+a"(v)); }
__device__ __forceinline__ void pinv(f32x4& v){ asm volatile("" : "+v"(v)); }

#define MFMA(A,B,C) __builtin_amdgcn_mfma_f32_16x16x32_f16((A),(B),(C),0,0,0)
#define ALOAD64(p)    __hip_atomic_load((p), __ATOMIC_RELAXED, __HIP_MEMORY_SCOPE_AGENT)
#define ALOAD32(p)    __hip_atomic_load((p), __ATOMIC_RELAXED, __HIP_MEMORY_SCOPE_AGENT)
#define ASTORE64(p,v) __hip_atomic_store((p), (v), __ATOMIC_RELAXED, __HIP_MEMORY_SCOPE_AGENT)
#define ASTORE16(p,v) __hip_atomic_store((p), (v), __ATOMIC_RELAXED, __HIP_MEMORY_SCOPE_AGENT)

// Persistent gate-sliced, layer-pipelined 2-layer LSTM — r15 MALL protocol with
// the global barrier taken OFF the critical path:
//  * pair-flags: wave w stages lines kt=2w,2w+1 whose producers are exactly
//    slices 2w,2w+1 -> poll ONE u32 (max-of-2 skew) instead of all 8 slices.
//  * triple-buffered h slots (mod-3): overwrite at step t+1 needs only
//    full-flag(t-1), checked at the END of step t (a full superstep of slack,
//    overlapped with staging loads) -> the 8-way sync is pipelined, not serial.
// 128 WGs x 256 thr: group=blockIdx%16, slice=blockIdx/16; wave owns 8 chans.
// Superstep t computes h0(t) [t<TT] and h1(t-1) [t>0]. All cross-WG data via
// relaxed agent-scope atomics (the only mechanism proven fast+correct here).
__global__ __launch_bounds__(256,1) __attribute__((amdgpu_waves_per_eu(1)))
void lstm_pers(
    const float* __restrict__ x,
    const float* __restrict__ Wih0, const float* __restrict__ Whh0,
    const float* __restrict__ bih0, const float* __restrict__ bhh0,
    const float* __restrict__ Wih1, const float* __restrict__ Whh1,
    const float* __restrict__ bih1, const float* __restrict__ bhh1,
    const float* __restrict__ W1, const float* __restrict__ b1,
    const float* __restrict__ W2, const float* __restrict__ b2,
    unsigned short* __restrict__ flags,
    _Float16* __restrict__ hb0, _Float16* __restrict__ hb1,
    float* __restrict__ out)
{
    // fragment-staging tile: [layer0 kt0..7 | layer1 kt0..7][128 u64] = 16 KB
    __shared__ __align__(16) u64 fsh[16*128];
    // per-wave store-transpose tiles
    __shared__ __align__(16) unsigned short twv[4][2][16][8];   // 2 KB
    __shared__ __align__(16) float epi[16*256 + 16*128];        // 24 KB (epilogue)

    const int tid = threadIdx.x;
    const int w   = tid >> 6;
    const int l   = tid & 63;
    const int lr  = l & 15;
    const int lk  = l >> 4;
    const int g   = blockIdx.x & (NG-1);
    const int s   = blockIdx.x >> 4;
    const int gbase = g * 16;
    const int cw  = s*32 + w*8;
    const int wid = s*4 + w;          // wave id in group == chanblock (0..31)

    u64* hb0u = (u64*)hb0;
    u64* hb1u = (u64*)hb1;

    // ---- resident weight fragments (MFMA A-operand), pinned into AGPRs ----
    half8 wA0[10][2];   // layer0: kt<8 -> Whh0 (K=256), kt=8,9 -> Wih0 (K=64)
    half8 wA1[16][2];   // layer1: kt<8 -> Whh1, kt>=8 -> Wih1
    f32x4 bias0v[2], bias1v[2];
#pragma unroll
    for (int m=0;m<2;++m){
        const int n = (lr&3)*HH + cw + m*4 + (lr>>2);
#pragma unroll
        for (int kt=0;kt<10;++kt){
            const float* src = (kt<8) ? (Whh0 + (size_t)n*HH + kt*32 + lk*8)
                                      : (Wih0 + (size_t)n*II + (kt-8)*32 + lk*8);
            wA0[kt][m] = cvt8v(src);
            pina(wA0[kt][m]);
        }
#pragma unroll
        for (int kt=0;kt<16;++kt){
            const float* src = (kt<8) ? (Whh1 + (size_t)n*HH + kt*32 + lk*8)
                                      : (Wih1 + (size_t)n*HH + (kt-8)*32 + lk*8);
            wA1[kt][m] = cvt8v(src);
            pina(wA1[kt][m]);
        }
        const int cD = cw + m*4 + lk;
#pragma unroll
        for (int j=0;j<4;++j){
            bias0v[m][j] = bih0[j*HH+cD] + bhh0[j*HH+cD];
            bias1v[m][j] = bih1[j*HH+cD] + bhh1[j*HH+cD];
        }
        pinv(bias0v[m]); pinv(bias1v[m]);
    }

    float c0s0=0.f, c0s1=0.f, c1s0=0.f, c1s1=0.f;
    unsigned short* fgrp = flags + (size_t)g*FST*8;
    const int fo = lk*32 + lr*2;      // per-lane frag offset (u64), + kt*128
    const int kt0 = 2*w;              // this wave's staged lines (pair w)

    // ---- x(0) register prefetch ----
    f32x4 xa, xb, xc, xd;
    {
        const float* xp = x + ((size_t)(gbase+lr)*TT)*II + lk*8;
        xa = *(const f32x4*)xp;      xb = *(const f32x4*)(xp+4);
        xc = *(const f32x4*)(xp+32); xd = *(const f32x4*)(xp+36);
    }

    half8 bh0[8] = {}, bh1[8] = {};   // current-step h fragments (B-operand)
    int s0 = 0, s1 = 2;               // h0 slot = t%3, h1 slot = (t-1)%3

    for (int t=0; t<=TT; ++t){
        f32x4 a0m0 = bias0v[0], a0m1 = bias0v[1];
        f32x4 a1m0 = bias1v[0], a1m1 = bias1v[1];

        // x-part of layer0 from prefetched registers
        if (t < TT){
            half8 bx0, bx1;
#pragma unroll
            for (int j=0;j<4;++j){
                bx0[j]   = (_Float16)xa[j];  bx0[4+j] = (_Float16)xb[j];
                bx1[j]   = (_Float16)xc[j];  bx1[4+j] = (_Float16)xd[j];
            }
            a0m0 = MFMA(wA0[8][0], bx0, a0m0);
            a0m1 = MFMA(wA0[8][1], bx0, a0m1);
            a0m0 = MFMA(wA0[9][0], bx1, a0m0);
            a0m1 = MFMA(wA0[9][1], bx1, a0m1);
        }

        if (t > 0){
            if (t < TT){
#pragma unroll
                for (int kt=0;kt<8;++kt){         // Whh0 * h0(t-1)
                    a0m0 = MFMA(wA0[kt][0], bh0[kt], a0m0);
                    a0m1 = MFMA(wA0[kt][1], bh0[kt], a0m1);
                }
            }
#pragma unroll
            for (int kt=0;kt<8;++kt){             // Wih1 * h0(t-1)
                a1m0 = MFMA(wA1[8+kt][0], bh0[kt], a1m0);
                a1m1 = MFMA(wA1[8+kt][1], bh0[kt], a1m1);
            }
            if (t >= 2){
#pragma unroll
                for (int kt=0;kt<8;++kt){         // Whh1 * h1(t-2)
                    a1m0 = MFMA(wA1[kt][0], bh1[kt], a1m0);
                    a1m1 = MFMA(wA1[kt][1], bh1[kt], a1m1);
                }
            }
        }

        // ---- activations -> wave-local LDS transpose tile ----
        if (t < TT){
            float ig=sigm(a0m0[0]), fg=sigm(a0m0[1]), gg=tanhf_(a0m0[2]), og=sigm(a0m0[3]);
            c0s0 = fg*c0s0 + ig*gg;
            twv[w][0][lr][lk]   = h2u(og*tanhf_(c0s0));
            float ig1=sigm(a0m1[0]), fg1=sigm(a0m1[1]), gg1=tanhf_(a0m1[2]), og1=sigm(a0m1[3]);
            c0s1 = fg1*c0s1 + ig1*gg1;
            twv[w][0][lr][lk+4] = h2u(og1*tanhf_(c0s1));
        }
        if (t > 0){
            float ig=sigm(a1m0[0]), fg=sigm(a1m0[1]), gg=tanhf_(a1m0[2]), og=sigm(a1m0[3]);
            c1s0 = fg*c1s0 + ig*gg;
            twv[w][1][lr][lk]   = h2u(og*tanhf_(c1s0));
            float ig1=sigm(a1m1[0]), fg1=sigm(a1m1[1]), gg1=tanhf_(a1m1[2]), og1=sigm(a1m1[3]);
            c1s1 = fg1*c1s1 + ig1*gg1;
            twv[w][1][lr][lk+4] = h2u(og1*tanhf_(c1s1));
        }
        asm volatile("s_waitcnt lgkmcnt(0)" ::: "memory");

        // ---- coalesced blocked piece stores: lanes 0..31, one u64 each ----
        // (overwrite of slot s0/s1 licensed by full-flag(t-2), verified at the
        //  end of superstep t-1 with a full superstep of slack)
        if (l < 32){
            const int row = l >> 1, hf = l & 1;
            if (t < TT){
                u64 v = *(const u64*)&twv[w][0][row][hf*4];
                ASTORE64(hb0u + ((size_t)(s0*NG + g))*1024 + wid*32 + l, v);
            }
            if (t > 0){
                u64 v = *(const u64*)&twv[w][1][row][hf*4];
                ASTORE64(hb1u + ((size_t)(s1*NG + g))*1024 + wid*32 + l, v);
            }
        }
        asm volatile("s_waitcnt vmcnt(0)" ::: "memory");   // this wave's stores visible
        __syncthreads();                                    // all 4 waves drained
        if (tid == 0)
            ASTORE16(&fgrp[(size_t)t*8 + s], (unsigned short)(t+1));  // WG flag

        if (t < TT){
            // x prefetch for t+1 — issued now so it hides under the polls.
            // GUARD: t+1 must be a valid time index (r16 bug: OOB read at t=511).
            if (t + 1 < TT){
                const float* xp = x + ((size_t)(gbase+lr)*TT + (t+1))*II + lk*8;
                xa = *(const f32x4*)xp;      xb = *(const f32x4*)(xp+4);
                xc = *(const f32x4*)(xp+32); xd = *(const f32x4*)(xp+36);
            }
            // ---- PAIR poll: wave w needs only slices 2w,2w+1 (one u32) ----
            {
                const unsigned patp = ((unsigned)(t+1)) | (((unsigned)(t+1))<<16);
                const unsigned* fp32 = (const unsigned*)(fgrp + (size_t)t*8);
                for (;;){
                    unsigned v = ALOAD32(fp32 + w);
                    if (v == patp) break;
                }
                __builtin_amdgcn_sched_barrier(0);
            }
            // ---- cooperative staging: wave w loads kt=2w,2w+1 -> LDS ----
            {
                const u64* T0 = hb0u + ((size_t)(s0*NG + g))*1024;
                u64 a0 = ALOAD64(T0 + kt0*128 + fo);
                u64 a1 = ALOAD64(T0 + kt0*128 + fo + 1);
                u64 b0 = ALOAD64(T0 + (kt0+1)*128 + fo);
                u64 b1 = ALOAD64(T0 + (kt0+1)*128 + fo + 1);
                fsh[kt0*128 + fo]       = a0;
                fsh[kt0*128 + fo + 1]   = a1;
                fsh[(kt0+1)*128 + fo]   = b0;
                fsh[(kt0+1)*128 + fo+1] = b1;
            }
            if (t >= 1){
                const u64* T1 = hb1u + ((size_t)(s1*NG + g))*1024;
                u64 a0 = ALOAD64(T1 + kt0*128 + fo);
                u64 a1 = ALOAD64(T1 + kt0*128 + fo + 1);
                u64 b0 = ALOAD64(T1 + (kt0+1)*128 + fo);
                u64 b1 = ALOAD64(T1 + (kt0+1)*128 + fo + 1);
                fsh[(8+kt0)*128 + fo]       = a0;
                fsh[(8+kt0)*128 + fo + 1]   = a1;
                fsh[(8+kt0+1)*128 + fo]     = b0;
                fsh[(8+kt0+1)*128 + fo + 1] = b1;
            }
            // ---- deferred FULL-group check of line t-1 (licenses stores t+1;
            //      one superstep old -> rarely blocks; overlaps staging) ----
            if (t >= 1){
                const u64 patf = 0x0001000100010001ULL * (u64)t;
                const u64* fpf = (const u64*)(fgrp + (size_t)(t-1)*8);
                for (;;){
                    u64 v = (l < 2) ? ALOAD64(fpf + l) : patf;
                    if (__all(v == patf)) break;
                }
            }
            __syncthreads();   // staging visible (implies lgkm drain)
            // ---- read fragments from LDS into B-registers ----
#pragma unroll
            for (int kt=0;kt<8;++kt){
                union { u64 u[2]; half8 h; } cv;
                cv.u[0] = fsh[kt*128 + fo];
                cv.u[1] = fsh[kt*128 + fo + 1];
                bh0[kt] = cv.h;
            }
            if (t >= 1){
#pragma unroll
                for (int kt=0;kt<8;++kt){
                    union { u64 u[2]; half8 h; } cv;
                    cv.u[0] = fsh[(8+kt)*128 + fo];
                    cv.u[1] = fsh[(8+kt)*128 + fo + 1];
                    bh1[kt] = cv.h;
                }
            }
        }
        // slot update: next s0 = (t+1)%3, next s1 = t%3
        s1 = s0;
        s0 = (s0 == 2) ? 0 : s0 + 1;
    }

    // ---- epilogue: slice 0 of each group computes the MLP head ----
    if (s == 0){
        {   // ensure all h1(TT-1) pieces are visible
            const u64 pat = 0x0001000100010001ULL * (u64)(TT+1);
            const u64* fp = (const u64*)(fgrp + (size_t)TT*8);
            for (;;){
                u64 v = (l < 2) ? ALOAD64(fp + l) : pat;
                if (__all(v == pat)) break;
            }
        }
        __syncthreads();
        float* hl  = epi;              // [16][256]
        float* zsh = epi + 16*256;     // [16][128]
        const u64* HL = hb1u + ((size_t)(((TT-1)%3)*NG + g))*1024;
        for (int i = tid; i < 1024; i += 256){
            const int r = i >> 6, q = i & 63;
            const size_t gi = (size_t)(q>>1)*32 + r*2 + (q&1);
            u64 v = ALOAD64(HL + gi);
            union { u64 u; _Float16 h[4]; } cv; cv.u = v;
#pragma unroll
            for (int e=0;e<4;++e) hl[r*256 + q*4 + e] = (float)cv.h[e];
        }
        __syncthreads();
        for (int idx = tid; idx < 2048; idx += 256){
            const int r = idx >> 7, j = idx & 127;
            const float* wrow = W1 + j*HH;
            const float* hr = hl + r*256;
            float ssum = b1[j];
            for (int k=0;k<HH;k+=4){
                f32x4 wv = *(const f32x4*)(wrow + k);
                ssum += hr[k]*wv[0] + hr[k+1]*wv[1] + hr[k+2]*wv[2] + hr[k+3]*wv[3];
            }
            zsh[r*128 + j] = tanhf_(ssum);
        }
        __syncthreads();
        for (int idx = tid; idx < 1536; idx += 256){
            const int r = idx / 96, o = idx - r*96;
            const float* wrow = W2 + o*128;
            const float* zr = zsh + r*128;
            float ssum = b2[o];
            for (int k=0;k<128;k+=4){
                f32x4 wv = *(const f32x4*)(wrow + k);
                ssum += zr[k]*wv[0] + zr[k+1]*wv[1] + zr[k+2]*wv[2] + zr[k+3]*wv[3];
            }
            out[(size_t)(gbase+r)*96 + o] = ssum;
        }
    }
}

extern "C" void kernel_launch(void* const* d_in, const int* in_sizes, int n_in,
                              void* d_out, int out_size, void* d_ws, size_t ws_size,
                              hipStream_t stream) {
    const float* x    = (const float*)d_in[0];
    const float* Wih0 = (const float*)d_in[1];
    const float* Whh0 = (const float*)d_in[2];
    const float* bih0 = (const float*)d_in[3];
    const float* bhh0 = (const float*)d_in[4];
    const float* Wih1 = (const float*)d_in[5];
    const float* Whh1 = (const float*)d_in[6];
    const float* bih1 = (const float*)d_in[7];
    const float* bhh1 = (const float*)d_in[8];
    const float* W1   = (const float*)d_in[9];
    const float* b1   = (const float*)d_in[10];
    const float* W2   = (const float*)d_in[11];
    const float* b2   = (const float*)d_in[12];

    // workspace: flags 16*520*16 B = 133,120 (zeroed; padded to 139,264)
    //            hb0/hb1 TRIPLE-buffered: 3 slots * 16 g * 8 KB = 393,216 B each
    unsigned short* flags = (unsigned short*)d_ws;
    _Float16* hb0 = (_Float16*)((char*)d_ws + 139264);
    _Float16* hb1 = (_Float16*)((char*)d_ws + 139264 + 393216);

    hipMemsetAsync(d_ws, 0, 139264, stream);

    hipLaunchKernelGGL(lstm_pers, dim3(NG*NS), dim3(256), 0, stream,
                       x, Wih0, Whh0, bih0, bhh0,
                       Wih1, Whh1, bih1, bhh1,
                       W1, b1, W2, b2,
                       flags, hb0, hb1, (float*)d_out);
}